// Round 11
// baseline (252.203 us; speedup 1.0000x reference)
//
#include <hip/hip_runtime.h>
#include <hip/hip_bf16.h>
#include <cstdint>

// EquivariantMPLayer restructured:
//   out = embed@W_res + relu(embed@Wu1 + aggr@Wu2 + b_upd)
//   aggr[c] = sum_{e: col[e]==c} relu(P1[row_e] + P2b[c] + dist_e*w_d)
//   P1 = embed@W1, P2b = embed@W2 + b_msg   (W_msg distributed over concat)
// R20/R21 (239.5us best): per-XCD replicated bins + big binpass blocks +
//   grid-strided cast fixed k01. aggregate back on top: FETCH 70MB vs 26MB
//   payload -> P1 (6.4MB) refetched ~7x (misses 4MB/XCD L2, ~21% miss rate,
//   latency-stall-bound at VALU 45% / HBM 18%).
// R22: (a) row-half partitioned aggregation: sort buckets (col<<1)|(row>=M/2)
//   -> per-node segment = [lo rows][hi rows]; aggregate runs 2 temporally
//   separated passes (LDS partials between) so per-pass P1 working set is
//   3.2MB -> L2-resident. (b) gemm_upd 128 rows/block: 24 weight-frag loads
//   amortize 4x (suspected hidden ~50us from per-32-row weight reload).

typedef __bf16 bf16x8 __attribute__((ext_vector_type(8)));
typedef float floatx4 __attribute__((ext_vector_type(4)));
typedef float floatx2 __attribute__((ext_vector_type(2)));
typedef unsigned int uintx4 __attribute__((ext_vector_type(4)));

#define NBINS 1024        // fine bin = col >> 6 -> 0..781 used (50000/64)
#define NCPY 8            // one binned copy per XCD
#define BINF_CAP 384      // per (bin,copy): mean 256, sigma ~15 -> 8-sigma
#define CAP_OUT 3072      // sorted stride: 2048 mean + 128-bucket pad4 headroom
#define CUR_STRIDE 32     // cursor stride in uints: one 128B line per cursor
#define EPB 8192          // edges per binpass block (4 chunks of 2048)
#define NPB 28            // aggregate: nodes per block (4 waves x 7)

__device__ __forceinline__ ushort f2bf(float f) {
  union { float f; uint i; } v; v.f = f;
  uint r = v.i + 0x7fff + ((v.i >> 16) & 1);   // RNE
  return (ushort)(r >> 16);
}
__device__ __forceinline__ bf16x8 load_frag(const ushort* p) {
  uint4 v = *(const uint4*)p;
  return __builtin_bit_cast(bf16x8, v);
}
__device__ __forceinline__ floatx2 pmax0(floatx2 a) {
#if __has_builtin(__builtin_elementwise_max)
  return __builtin_elementwise_max(a, (floatx2)(0.f));
#else
  floatx2 r; r.x = fmaxf(a.x, 0.f); r.y = fmaxf(a.y, 0.f); return r;
#endif
}
// 2 fp8 (low 16 bits of qu) -> 2 f32 in one VALU op where available
__device__ __forceinline__ floatx2 cvtpk2(uint qu) {
#if __has_builtin(__builtin_amdgcn_cvt_pk_f32_fp8)
  return __builtin_amdgcn_cvt_pk_f32_fp8((int)qu, false);
#else
  floatx2 o = {__builtin_amdgcn_cvt_f32_fp8((int)qu, 0),
               __builtin_amdgcn_cvt_f32_fp8((int)qu, 1)};
  return o;
#endif
}

struct WSrc { const float* s[5]; };

// ---- K01: fused bf16 cast (+weight transpose) and edge binning pass ----
// blockIdx [0, bb)           : binpass — 8192 edges, two scans
// blockIdx [bb, bb+nb_cast)  : cast embed f32 -> bf16, 8 float4/thread
// blockIdx [bb+nb_cast, +5)  : weight transpose-cast
__global__ __launch_bounds__(256) void k01_cast_bin(
    const float* __restrict__ embed, ushort* __restrict__ Eb, int n4, int nb_cast,
    WSrc ws, ushort* __restrict__ Wt,
    const int* __restrict__ ei, int E,
    uint* __restrict__ bin_cursor, uint* __restrict__ binned, int bb)
{
  __shared__ uint hist[NBINS];
  __shared__ uint sbase[NBINS];
  __shared__ uint lcur[NBINS];

  if ((int)blockIdx.x >= bb) {
    int cb = blockIdx.x - bb;
    if (cb < nb_cast) {
      int base = cb * 2048 + threadIdx.x;
#pragma unroll
      for (int k = 0; k < 8; ++k) {
        int i = base + k * 256;
        if (i < n4) {
          float4 v = ((const float4*)embed)[i];
          ushort4 o;
          o.x = f2bf(v.x); o.y = f2bf(v.y); o.z = f2bf(v.z); o.w = f2bf(v.w);
          ((ushort4*)Eb)[i] = o;
        }
      }
      return;
    }
    int wb = cb - nb_cast;
    const float* s = ws.s[wb];
    ushort* d = Wt + wb * 16384;
    for (int i = threadIdx.x; i < 16384; i += 256) {
      int k = i >> 7, n = i & 127;
      d[n * 128 + k] = f2bf(s[i]);
    }
    return;
  }

  // ---- binpass: 8192 edges, scan 1 (cols only) -> histogram ----
  const int t = threadIdx.x;
#pragma unroll
  for (int k = 0; k < NBINS / 256; ++k) hist[t + k * 256] = 0;
  __syncthreads();

  const int blk0 = blockIdx.x * EPB;
#pragma unroll
  for (int c = 0; c < EPB / 2048; ++c) {
    int e0 = blk0 + c * 2048 + t * 8;
    if (e0 < E) {
      int4 c0 = ((const int4*)(ei + E + e0))[0];
      int4 c1 = ((const int4*)(ei + E + e0))[1];
      int cc[8];
      cc[0]=c0.x; cc[1]=c0.y; cc[2]=c0.z; cc[3]=c0.w;
      cc[4]=c1.x; cc[5]=c1.y; cc[6]=c1.z; cc[7]=c1.w;
#pragma unroll
      for (int j = 0; j < 8; ++j)
        if (e0 + j < E) atomicAdd(&hist[cc[j] >> 6], 1u);
    }
  }
  __syncthreads();

  // one cursor round for all 8192 edges
  const int cpy = blockIdx.x & 7;   // block->XCD round-robin heuristic
  uint* cur = bin_cursor + (size_t)cpy * NBINS * CUR_STRIDE;
#pragma unroll
  for (int k = 0; k < NBINS / 256; ++k) {
    int b2 = t + k * 256;
    uint h = hist[b2];
    sbase[b2] = h ? atomicAdd(cur + (size_t)b2 * CUR_STRIDE, h) : 0u;
    lcur[b2] = 0;
  }
  __syncthreads();

  // scan 2: reload (cols L2-hot) + scatter into this copy's bins
  uint* mybin = binned + (size_t)cpy * NBINS * BINF_CAP;
#pragma unroll
  for (int c = 0; c < EPB / 2048; ++c) {
    int e0 = blk0 + c * 2048 + t * 8;
    if (e0 < E) {
      int4 r0 = ((const int4*)(ei + e0))[0];
      int4 r1 = ((const int4*)(ei + e0))[1];
      int4 c0 = ((const int4*)(ei + E + e0))[0];
      int4 c1 = ((const int4*)(ei + E + e0))[1];
      int rr[8], cc[8];
      rr[0]=r0.x; rr[1]=r0.y; rr[2]=r0.z; rr[3]=r0.w;
      rr[4]=r1.x; rr[5]=r1.y; rr[6]=r1.z; rr[7]=r1.w;
      cc[0]=c0.x; cc[1]=c0.y; cc[2]=c0.z; cc[3]=c0.w;
      cc[4]=c1.x; cc[5]=c1.y; cc[6]=c1.z; cc[7]=c1.w;
#pragma unroll
      for (int j = 0; j < 8; ++j) {
        if (e0 + j < E) {
          int b = cc[j] >> 6;
          uint ofs = atomicAdd(&lcur[b], 1u);
          uint idx = sbase[b] + ofs;
          if (idx < BINF_CAP)
            mybin[(size_t)b * BINF_CAP + idx] = ((uint)cc[j] << 16) | (uint)rr[j];
        }
      }
    }
  }
}

// ---- K2: proj GEMM (MFMA) + per-64-col-bin counting sort (8 segments) ----
// Sort buckets keyed (col&63)<<1 | (row>=M/2): each col's run is
// [lo-row recs][hi-row recs], both 4-rec aligned. ncnt packs lo|hi<<16.
// MFMA 16x16x32 bf16 fragment layouts (verified m89/m120):
//   A: lane l, j -> A[m=l&15][k=(l>>4)*8+j];  B: lane l, j -> B[k=(l>>4)*8+j][n=l&15]
//   D: lane l, i -> D[m=(l>>4)*4+i][n=l&15]
__global__ __launch_bounds__(256) void k2_proj_sort(
    const ushort* __restrict__ Ab, int M, int rt,
    const ushort* __restrict__ W1t, const ushort* __restrict__ W2t,
    const float* __restrict__ b_msg, const float* __restrict__ pos,
    unsigned char* __restrict__ P1, ushort* __restrict__ P2b,
    const uint* __restrict__ bin_cursor, const uint* __restrict__ binned,
    uint* __restrict__ sorted, int* __restrict__ nstart, int* __restrict__ ncnt)
{
  // LDS (sort branch only; ~21 KB, GEMM occupancy unaffected)
  __shared__ ushort sdist[NCPY * BINF_CAP];   // 6 KB per-edge bf16 dist cache
  __shared__ uint   srt[CAP_OUT];             // 12 KB col-sorted recs
  __shared__ float  spos[64 * 3];             // 768 B
  __shared__ uint   h128[128], st128[128], lc128[128];
  __shared__ uint   ccnt[NCPY];
  __shared__ uint   stot;

  if ((int)blockIdx.x >= rt) {
    // ---- per-bin counting sort over the bin's 8 XCD segments ----
    const int bin = blockIdx.x - rt;
    const int col0 = bin * 64;
    const int ncol = min(64, M - col0);
    const int tid = threadIdx.x;
    const uint halfM = (uint)(M >> 1);

    if (tid < 128) { h128[tid] = 0; lc128[tid] = 0; }
    if (tid < NCPY)
      ccnt[tid] = min(bin_cursor[((size_t)tid * NBINS + bin) * CUR_STRIDE],
                      (uint)BINF_CAP);
    for (int i = tid; i < ncol * 3; i += 256) spos[i] = pos[(size_t)col0 * 3 + i];
    __syncthreads();

    // pass 1: dist (pos[row] gathers hide under co-resident GEMM) + histogram
    for (int c = 0; c < NCPY; ++c) {
      const int cnt = (int)ccnt[c];
      const uint* src = binned + ((size_t)c * NBINS + bin) * BINF_CAP;
      for (int i = tid; i < cnt; i += 256) {
        uint rc = src[i];
        uint row = rc & 0xffffu, c6 = (rc >> 16) & 63u;
        float dx = spos[c6 * 3 + 0] - pos[(size_t)row * 3 + 0];
        float dy = spos[c6 * 3 + 1] - pos[(size_t)row * 3 + 1];
        float dz = spos[c6 * 3 + 2] - pos[(size_t)row * 3 + 2];
        sdist[c * BINF_CAP + i] = f2bf(dx * dx + dy * dy + dz * dz);
        uint bk = (c6 << 1) | (row >= halfM ? 1u : 0u);
        atomicAdd(&h128[bk], 1u);
      }
    }
    __syncthreads();

    // exclusive prefix over 128 buckets, each padded to 4 recs (16B align)
    if (tid == 0) {
      uint run = 0;
      for (int c = 0; c < 128; ++c) { st128[c] = run; run += (h128[c] + 3u) & ~3u; }
      stot = min(run, (uint)CAP_OUT);
    }
    __syncthreads();

    // pass 2: scatter into LDS at sorted positions (src re-read is L2-hot)
    for (int c = 0; c < NCPY; ++c) {
      const int cnt = (int)ccnt[c];
      const uint* src = binned + ((size_t)c * NBINS + bin) * BINF_CAP;
      for (int i = tid; i < cnt; i += 256) {
        uint rc = src[i];
        uint row = rc & 0xffffu, c6 = (rc >> 16) & 63u;
        uint bk = (c6 << 1) | (row >= halfM ? 1u : 0u);
        uint p = st128[bk] + atomicAdd(&lc128[bk], 1u);
        if (p < CAP_OUT)
          srt[p] = (row << 16) | (uint)sdist[c * BINF_CAP + i];
      }
    }
    __syncthreads();

    // sequential writeout + per-node index (lo start; hi = lo + pad4(cnt_lo))
    const size_t obase = (size_t)bin * CAP_OUT;
    for (int i = tid; i < (int)stot; i += 256)
      sorted[obase + i] = srt[i];
    if (tid < ncol) {
      uint lo = h128[2 * tid], hi = h128[2 * tid + 1];
      nstart[col0 + tid] = (int)(obase + st128[2 * tid]);
      ncnt[col0 + tid] = (int)(lo | (hi << 16));
    }
    return;
  }

  // ---- proj: P1 = fp8(Eb@W1t^T), P2b = bf16(Eb@W2t^T + b_msg) ----
  const int wv = threadIdx.x >> 6, lane = threadIdx.x & 63;
  const int q = lane >> 4, lr = lane & 15;
  const int m0 = blockIdx.x * 32;
  const int n0 = wv * 32;

  const ushort* Wt2[2] = {W1t, W2t};
  bf16x8 bfr[2][2][4];
#pragma unroll
  for (int ws = 0; ws < 2; ++ws)
#pragma unroll
    for (int nt = 0; nt < 2; ++nt) {
      int colc = n0 + nt * 16 + lr;
#pragma unroll
      for (int kc = 0; kc < 4; ++kc)
        bfr[ws][nt][kc] = load_frag(Wt2[ws] + colc * 128 + kc * 32 + q * 8);
    }

  floatx4 z = {0.f, 0.f, 0.f, 0.f};
  floatx4 acc[2][2][2];
#pragma unroll
  for (int ws = 0; ws < 2; ++ws)
#pragma unroll
    for (int mt = 0; mt < 2; ++mt)
#pragma unroll
      for (int nt = 0; nt < 2; ++nt) acc[ws][mt][nt] = z;

  const int r0 = min(m0 + lr, M - 1);
  const int r1 = min(m0 + 16 + lr, M - 1);
#pragma unroll
  for (int kc = 0; kc < 4; ++kc) {
    bf16x8 a0 = load_frag(Ab + (size_t)r0 * 128 + kc * 32 + q * 8);
    bf16x8 a1 = load_frag(Ab + (size_t)r1 * 128 + kc * 32 + q * 8);
#pragma unroll
    for (int ws = 0; ws < 2; ++ws)
#pragma unroll
      for (int nt = 0; nt < 2; ++nt) {
        acc[ws][0][nt] = __builtin_amdgcn_mfma_f32_16x16x32_bf16(a0, bfr[ws][nt][kc], acc[ws][0][nt], 0, 0, 0);
        acc[ws][1][nt] = __builtin_amdgcn_mfma_f32_16x16x32_bf16(a1, bfr[ws][nt][kc], acc[ws][1][nt], 0, 0, 0);
      }
  }

#pragma unroll
  for (int nt = 0; nt < 2; ++nt) {
    int colc = n0 + nt * 16 + lr;
    float bias = b_msg[colc];
#pragma unroll
    for (int mt = 0; mt < 2; ++mt)
#pragma unroll
      for (int i = 0; i < 4; ++i) {
        int r = m0 + mt * 16 + q * 4 + i;
        if (r < M) {
          int p8 = __builtin_amdgcn_cvt_pk_fp8_f32(acc[0][mt][nt][i], 0.f, 0, false);
          P1[(size_t)r * 128 + colc] = (unsigned char)(p8 & 0xff);
          P2b[(size_t)r * 128 + colc] = f2bf(acc[1][mt][nt][i] + bias);
        }
      }
  }
}

// ---- K3: aggregate — two row-half passes, LDS partials between ----
// Pass 0: every wave sums its 7 nodes' lo-row edges (P1 rows < M/2, 3.2MB
// working set -> per-XCD-L2-resident), parks partials in LDS. Pass 1: hi
// rows, add, write. All ~1786 blocks co-resident -> passes stay aligned.
__global__ __launch_bounds__(256) void aggregate(const int* __restrict__ ncnt,
                                                 const int* __restrict__ nstart,
                                                 const uint* __restrict__ sorted,
                                                 const unsigned char* __restrict__ P1,
                                                 const ushort* __restrict__ P2b,
                                                 const float* __restrict__ wd,
                                                 ushort* __restrict__ aggr, int M)
{
  __shared__ float2 accS[NPB][64];   // 14 KB wave-private partials

  const int lane = threadIdx.x & 63;
  const int ch = lane * 2;
  const int w = threadIdx.x >> 6;
  const int nbase = blockIdx.x * NPB + w * 7;

  float2 wl = *(const float2*)(wd + ch);
  floatx2 wv = {wl.x, wl.y};

  // rec = (row<<16) | dist_bf16.  P1 row stride = 128B, so
  // voffset = ((rec>>16)<<7) | ch == ((rec>>9) & 0x7fff80) | ch  (32-bit)
#define EDGE_BODY(rec, acc)                                             \
  {                                                                     \
    float d = __int_as_float((int)((rec) << 16));                       \
    uint off = (((rec) >> 9) & 0x007fff80u) | (uint)ch;                 \
    uint qu = (uint)*(const ushort*)(P1 + off);                         \
    floatx2 u = __builtin_elementwise_fma((floatx2)(d), wv, p2);        \
    floatx2 tt = cvtpk2(qu) + u;                                        \
    acc += pmax0(tt);                                                   \
  }

  // ---- pass 0: lo-row halves -> LDS partials ----
  for (int k = 0; k < 7; ++k) {
    int n = nbase + k;
    if (n >= M) break;
    uint p2u = *(const uint*)(P2b + (size_t)n * 128 + ch);
    floatx2 p2 = {__int_as_float((int)(p2u << 16)),
                  __int_as_float((int)(p2u & 0xffff0000u))};
    const int cnt = ncnt[n] & 0xffff;
    const uint* base = sorted + nstart[n];
    floatx2 accA = {0.f, 0.f}, accB = {0.f, 0.f};
    int i = 0;
    for (; i + 8 <= cnt; i += 8) {
      uintx4 ra = __builtin_nontemporal_load((const uintx4*)(base + i));
      uintx4 rb = __builtin_nontemporal_load((const uintx4*)(base + i + 4));
      EDGE_BODY(ra.x, accA) EDGE_BODY(ra.y, accB)
      EDGE_BODY(ra.z, accA) EDGE_BODY(ra.w, accB)
      EDGE_BODY(rb.x, accA) EDGE_BODY(rb.y, accB)
      EDGE_BODY(rb.z, accA) EDGE_BODY(rb.w, accB)
    }
    for (; i < cnt; ++i) { uint rc = base[i]; EDGE_BODY(rc, accA) }
    floatx2 acc = accA + accB;
    accS[w * 7 + k][lane] = make_float2(acc.x, acc.y);
  }

  // wave-private LDS rows: no block barrier needed between passes

  // ---- pass 1: hi-row halves + writeout ----
  for (int k = 0; k < 7; ++k) {
    int n = nbase + k;
    if (n >= M) break;
    uint p2u = *(const uint*)(P2b + (size_t)n * 128 + ch);
    floatx2 p2 = {__int_as_float((int)(p2u << 16)),
                  __int_as_float((int)(p2u & 0xffff0000u))};
    uint pc = (uint)ncnt[n];
    int clo = (int)(pc & 0xffffu);
    int cnt = (int)(pc >> 16);
    const uint* base = sorted + nstart[n] + ((clo + 3) & ~3);
    float2 ls = accS[w * 7 + k][lane];
    floatx2 accA = {ls.x, ls.y}, accB = {0.f, 0.f};
    int i = 0;
    for (; i + 8 <= cnt; i += 8) {
      uintx4 ra = __builtin_nontemporal_load((const uintx4*)(base + i));
      uintx4 rb = __builtin_nontemporal_load((const uintx4*)(base + i + 4));
      EDGE_BODY(ra.x, accA) EDGE_BODY(ra.y, accB)
      EDGE_BODY(ra.z, accA) EDGE_BODY(ra.w, accB)
      EDGE_BODY(rb.x, accA) EDGE_BODY(rb.y, accB)
      EDGE_BODY(rb.z, accA) EDGE_BODY(rb.w, accB)
    }
    for (; i < cnt; ++i) { uint rc = base[i]; EDGE_BODY(rc, accA) }
    floatx2 acc = accA + accB;
    uint o = (uint)f2bf(acc.x) | ((uint)f2bf(acc.y) << 16);
    *(uint*)(aggr + (size_t)n * 128 + ch) = o;   // gemm_upd reads it next
  }
#undef EDGE_BODY
}

// ---- K4: out = Eb@Wrt^T + relu(Eb@Wu1t^T + Gb@Wu2t^T + b_upd) ----
// R22: 128 rows/block — weight fragments (24 x 16B/lane) load once,
// amortized over 4 row-chunks.
__global__ __launch_bounds__(256) void gemm_upd_mfma(
    const ushort* __restrict__ Eb, const ushort* __restrict__ Gb, int M,
    const ushort* __restrict__ Wu1t, const ushort* __restrict__ Wu2t,
    const ushort* __restrict__ Wrt, const float* __restrict__ b_upd,
    float* __restrict__ out)
{
  const int wv = threadIdx.x >> 6, lane = threadIdx.x & 63;
  const int q = lane >> 4, lr = lane & 15;
  const int m0 = blockIdx.x * 128;
  const int n0 = wv * 32;

  bf16x8 b1[2][4], b2[2][4], br[2][4];
#pragma unroll
  for (int nt = 0; nt < 2; ++nt) {
    int colc = n0 + nt * 16 + lr;
#pragma unroll
    for (int kc = 0; kc < 4; ++kc) {
      b1[nt][kc] = load_frag(Wu1t + colc * 128 + kc * 32 + q * 8);
      b2[nt][kc] = load_frag(Wu2t + colc * 128 + kc * 32 + q * 8);
      br[nt][kc] = load_frag(Wrt  + colc * 128 + kc * 32 + q * 8);
    }
  }

  floatx4 z = {0.f, 0.f, 0.f, 0.f};

  for (int rc = 0; rc < 4; ++rc) {
    const int mb = m0 + rc * 32;
    if (mb >= M) break;

    floatx4 acc_u[2][2], acc_r[2][2];
#pragma unroll
    for (int mt = 0; mt < 2; ++mt)
#pragma unroll
      for (int nt = 0; nt < 2; ++nt) { acc_u[mt][nt] = z; acc_r[mt][nt] = z; }

    const int r0 = min(mb + lr, M - 1);
    const int r1 = min(mb + 16 + lr, M - 1);
#pragma unroll
    for (int kc = 0; kc < 4; ++kc) {
      bf16x8 ae0 = load_frag(Eb + (size_t)r0 * 128 + kc * 32 + q * 8);
      bf16x8 ae1 = load_frag(Eb + (size_t)r1 * 128 + kc * 32 + q * 8);
      bf16x8 ag0 = load_frag(Gb + (size_t)r0 * 128 + kc * 32 + q * 8);
      bf16x8 ag1 = load_frag(Gb + (size_t)r1 * 128 + kc * 32 + q * 8);
#pragma unroll
      for (int nt = 0; nt < 2; ++nt) {
        acc_u[0][nt] = __builtin_amdgcn_mfma_f32_16x16x32_bf16(ae0, b1[nt][kc], acc_u[0][nt], 0, 0, 0);
        acc_u[1][nt] = __builtin_amdgcn_mfma_f32_16x16x32_bf16(ae1, b1[nt][kc], acc_u[1][nt], 0, 0, 0);
        acc_u[0][nt] = __builtin_amdgcn_mfma_f32_16x16x32_bf16(ag0, b2[nt][kc], acc_u[0][nt], 0, 0, 0);
        acc_u[1][nt] = __builtin_amdgcn_mfma_f32_16x16x32_bf16(ag1, b2[nt][kc], acc_u[1][nt], 0, 0, 0);
        acc_r[0][nt] = __builtin_amdgcn_mfma_f32_16x16x32_bf16(ae0, br[nt][kc], acc_r[0][nt], 0, 0, 0);
        acc_r[1][nt] = __builtin_amdgcn_mfma_f32_16x16x32_bf16(ae1, br[nt][kc], acc_r[1][nt], 0, 0, 0);
      }
    }

#pragma unroll
    for (int nt = 0; nt < 2; ++nt) {
      int colc = n0 + nt * 16 + lr;
      float bias = b_upd[colc];
#pragma unroll
      for (int mt = 0; mt < 2; ++mt)
#pragma unroll
        for (int i = 0; i < 4; ++i) {
          int r = mb + mt * 16 + q * 4 + i;
          if (r < M)
            out[(size_t)r * 128 + colc] = acc_r[mt][nt][i] + fmaxf(acc_u[mt][nt][i] + bias, 0.f);
        }
    }
  }
}

extern "C" void kernel_launch(void* const* d_in, const int* in_sizes, int n_in,
                              void* d_out, int out_size, void* d_ws, size_t ws_size,
                              hipStream_t stream)
{
  const float* embed = (const float*)d_in[0];
  const float* pos   = (const float*)d_in[1];
  const int*   ei    = (const int*)d_in[2];
  const float* W_res = (const float*)d_in[3];
  const float* W_msg = (const float*)d_in[4];
  const float* b_msg = (const float*)d_in[5];
  const float* W_upd = (const float*)d_in[6];
  const float* b_upd = (const float*)d_in[7];
  float* out = (float*)d_out;

  const int M = in_sizes[0] / 128;   // 50000 (< 2^16, required for packed recs)
  const int E = in_sizes[2] / 2;     // 1.6M

  // Workspace (~74 MB); all segments 16-B aligned
  ushort* Eb = (ushort*)d_ws;                          // M*128 bf16
  unsigned char* P1f8 = (unsigned char*)(Eb + (size_t)M * 128);  // M*128 fp8
  ushort* P2b = (ushort*)(P1f8 + (size_t)M * 128);     // M*128 bf16
  ushort* Gb  = P2b + (size_t)M * 128;                 // M*128 bf16
  ushort* Wt  = Gb  + (size_t)M * 128;                 // 5 x 128x128 bf16 (transposed)
  uint*   binned = (uint*)(Wt + 5 * 16384);            // NCPY*NBINS*BINF_CAP
  uint*   sorted = binned + (size_t)NCPY * NBINS * BINF_CAP;  // NBINS*CAP_OUT
  int*    nstart = (int*)(sorted + (size_t)NBINS * CAP_OUT);  // M
  int*    ncnt   = nstart + M;                         // M (lo | hi<<16)
  uint*   bin_cursor = (uint*)(ncnt + M);              // NCPY*NBINS*CUR_STRIDE

  // zero padded per-copy bin cursors (1 MB)
  (void)hipMemsetAsync(bin_cursor, 0,
                       (size_t)NCPY * NBINS * CUR_STRIDE * sizeof(uint), stream);

  WSrc wsrc;
  wsrc.s[0] = W_msg;               // W1
  wsrc.s[1] = W_msg + 128 * 128;   // W2
  wsrc.s[2] = W_res;               // Wres
  wsrc.s[3] = W_upd;               // Wu1
  wsrc.s[4] = W_upd + 128 * 128;   // Wu2

  int n4 = M * 128 / 4;
  int nb_cast = (n4 + 2047) / 2048;          // grid-strided: 8 float4/thread
  int bb = (E + EPB - 1) / EPB;              // 196 binpass blocks
  // fused cast + binpass: binpass blocks first (critical path),
  // cast blocks fill the machine around them
  k01_cast_bin<<<bb + nb_cast + 5, 256, 0, stream>>>(
      embed, Eb, n4, nb_cast, wsrc, Wt, ei, E, bin_cursor, binned, bb);

  int rt = (M + 31) / 32;
  int nb2 = (M + 63) / 64;   // 782 used fine bins
  k2_proj_sort<<<rt + nb2, 256, 0, stream>>>(
      Eb, M, rt, Wt, Wt + 16384, b_msg, pos, P1f8, P2b,
      bin_cursor, binned, sorted, nstart, ncnt);

  // two-pass aggregate: ~1786 blocks, all co-resident
  int ab = (M + NPB - 1) / NPB;
  aggregate<<<ab, 256, 0, stream>>>(ncnt, nstart, sorted, P1f8, P2b,
                                    W_msg + 256 * 128, Gb, M);

  int rt4 = (M + 127) / 128;   // 391 blocks, weights amortized 4x
  gemm_upd_mfma<<<rt4, 256, 0, stream>>>(Eb, Gb, M, Wt + 3 * 16384, Wt + 4 * 16384,
                                         Wt + 2 * 16384, b_upd, out);
}

// Round 12
// 227.920 us; speedup vs baseline: 1.1065x; 1.1065x over previous
//
#include <hip/hip_runtime.h>
#include <hip/hip_bf16.h>
#include <cstdint>

// EquivariantMPLayer restructured:
//   out = embed@W_res + relu(embed@Wu1 + aggr@Wu2 + b_upd)
//   aggr[c] = sum_{e: col[e]==c} relu(P1[row_e] + P2b[c] + dist_e*w_d)
//   P1 = embed@W1, P2b = embed@W2 + b_msg   (W_msg distributed over concat)
// R21 (239.5us): per-XCD replicated bins + 8192-edge binpass + grid-strided
//   cast. aggregate 58.5us ~= random-line gather floor (205MB @ ~3.6TB/s).
// R22 (252us): row-half partitioned aggregate REGRESSED — FETCH 70->55MB but
//   dur +19us: halved segments killed gather depth + doubled per-node
//   overhead (latency*parallelism-bound, not BW-bound). gemm_upd 128-row
//   amortization WON ~6.6us (total delta decomposition).
// R23: revert aggregate+sort to R21 exactly; keep gemm_upd 128 rows/block.

typedef __bf16 bf16x8 __attribute__((ext_vector_type(8)));
typedef float floatx4 __attribute__((ext_vector_type(4)));
typedef float floatx2 __attribute__((ext_vector_type(2)));
typedef unsigned int uintx4 __attribute__((ext_vector_type(4)));

#define NBINS 1024        // fine bin = col >> 6 -> 0..781 used (50000/64)
#define NCPY 8            // one binned copy per XCD
#define BINF_CAP 384      // per (bin,copy): mean 256, sigma ~15 -> 8-sigma
#define CAP_OUT 2816      // sorted stride: 64 cols * (mean 32 + pad4), mult of 4
#define CUR_STRIDE 32     // cursor stride in uints: one 128B line per cursor
#define EPB 8192          // edges per binpass block (4 chunks of 2048)

__device__ __forceinline__ ushort f2bf(float f) {
  union { float f; uint i; } v; v.f = f;
  uint r = v.i + 0x7fff + ((v.i >> 16) & 1);   // RNE
  return (ushort)(r >> 16);
}
__device__ __forceinline__ bf16x8 load_frag(const ushort* p) {
  uint4 v = *(const uint4*)p;
  return __builtin_bit_cast(bf16x8, v);
}
__device__ __forceinline__ floatx2 pmax0(floatx2 a) {
#if __has_builtin(__builtin_elementwise_max)
  return __builtin_elementwise_max(a, (floatx2)(0.f));
#else
  floatx2 r; r.x = fmaxf(a.x, 0.f); r.y = fmaxf(a.y, 0.f); return r;
#endif
}
// 2 fp8 (low 16 bits of qu) -> 2 f32 in one VALU op where available
__device__ __forceinline__ floatx2 cvtpk2(uint qu) {
#if __has_builtin(__builtin_amdgcn_cvt_pk_f32_fp8)
  return __builtin_amdgcn_cvt_pk_f32_fp8((int)qu, false);
#else
  floatx2 o = {__builtin_amdgcn_cvt_f32_fp8((int)qu, 0),
               __builtin_amdgcn_cvt_f32_fp8((int)qu, 1)};
  return o;
#endif
}

struct WSrc { const float* s[5]; };

// ---- K01: fused bf16 cast (+weight transpose) and edge binning pass ----
// blockIdx [0, bb)           : binpass — 8192 edges, two scans
// blockIdx [bb, bb+nb_cast)  : cast embed f32 -> bf16, 8 float4/thread
// blockIdx [bb+nb_cast, +5)  : weight transpose-cast
__global__ __launch_bounds__(256) void k01_cast_bin(
    const float* __restrict__ embed, ushort* __restrict__ Eb, int n4, int nb_cast,
    WSrc ws, ushort* __restrict__ Wt,
    const int* __restrict__ ei, int E,
    uint* __restrict__ bin_cursor, uint* __restrict__ binned, int bb)
{
  __shared__ uint hist[NBINS];
  __shared__ uint sbase[NBINS];
  __shared__ uint lcur[NBINS];

  if ((int)blockIdx.x >= bb) {
    int cb = blockIdx.x - bb;
    if (cb < nb_cast) {
      int base = cb * 2048 + threadIdx.x;
#pragma unroll
      for (int k = 0; k < 8; ++k) {
        int i = base + k * 256;
        if (i < n4) {
          float4 v = ((const float4*)embed)[i];
          ushort4 o;
          o.x = f2bf(v.x); o.y = f2bf(v.y); o.z = f2bf(v.z); o.w = f2bf(v.w);
          ((ushort4*)Eb)[i] = o;
        }
      }
      return;
    }
    int wb = cb - nb_cast;
    const float* s = ws.s[wb];
    ushort* d = Wt + wb * 16384;
    for (int i = threadIdx.x; i < 16384; i += 256) {
      int k = i >> 7, n = i & 127;
      d[n * 128 + k] = f2bf(s[i]);
    }
    return;
  }

  // ---- binpass: 8192 edges, scan 1 (cols only) -> histogram ----
  const int t = threadIdx.x;
#pragma unroll
  for (int k = 0; k < NBINS / 256; ++k) hist[t + k * 256] = 0;
  __syncthreads();

  const int blk0 = blockIdx.x * EPB;
#pragma unroll
  for (int c = 0; c < EPB / 2048; ++c) {
    int e0 = blk0 + c * 2048 + t * 8;
    if (e0 < E) {
      int4 c0 = ((const int4*)(ei + E + e0))[0];
      int4 c1 = ((const int4*)(ei + E + e0))[1];
      int cc[8];
      cc[0]=c0.x; cc[1]=c0.y; cc[2]=c0.z; cc[3]=c0.w;
      cc[4]=c1.x; cc[5]=c1.y; cc[6]=c1.z; cc[7]=c1.w;
#pragma unroll
      for (int j = 0; j < 8; ++j)
        if (e0 + j < E) atomicAdd(&hist[cc[j] >> 6], 1u);
    }
  }
  __syncthreads();

  // one cursor round for all 8192 edges
  const int cpy = blockIdx.x & 7;   // block->XCD round-robin heuristic
  uint* cur = bin_cursor + (size_t)cpy * NBINS * CUR_STRIDE;
#pragma unroll
  for (int k = 0; k < NBINS / 256; ++k) {
    int b2 = t + k * 256;
    uint h = hist[b2];
    sbase[b2] = h ? atomicAdd(cur + (size_t)b2 * CUR_STRIDE, h) : 0u;
    lcur[b2] = 0;
  }
  __syncthreads();

  // scan 2: reload (cols L2-hot) + scatter into this copy's bins
  uint* mybin = binned + (size_t)cpy * NBINS * BINF_CAP;
#pragma unroll
  for (int c = 0; c < EPB / 2048; ++c) {
    int e0 = blk0 + c * 2048 + t * 8;
    if (e0 < E) {
      int4 r0 = ((const int4*)(ei + e0))[0];
      int4 r1 = ((const int4*)(ei + e0))[1];
      int4 c0 = ((const int4*)(ei + E + e0))[0];
      int4 c1 = ((const int4*)(ei + E + e0))[1];
      int rr[8], cc[8];
      rr[0]=r0.x; rr[1]=r0.y; rr[2]=r0.z; rr[3]=r0.w;
      rr[4]=r1.x; rr[5]=r1.y; rr[6]=r1.z; rr[7]=r1.w;
      cc[0]=c0.x; cc[1]=c0.y; cc[2]=c0.z; cc[3]=c0.w;
      cc[4]=c1.x; cc[5]=c1.y; cc[6]=c1.z; cc[7]=c1.w;
#pragma unroll
      for (int j = 0; j < 8; ++j) {
        if (e0 + j < E) {
          int b = cc[j] >> 6;
          uint ofs = atomicAdd(&lcur[b], 1u);
          uint idx = sbase[b] + ofs;
          if (idx < BINF_CAP)
            mybin[(size_t)b * BINF_CAP + idx] = ((uint)cc[j] << 16) | (uint)rr[j];
        }
      }
    }
  }
}

// ---- K2: proj GEMM (MFMA) + per-64-col-bin counting sort (8 segments) ----
// MFMA 16x16x32 bf16 fragment layouts (verified m89/m120):
//   A: lane l, j -> A[m=l&15][k=(l>>4)*8+j];  B: lane l, j -> B[k=(l>>4)*8+j][n=l&15]
//   D: lane l, i -> D[m=(l>>4)*4+i][n=l&15]
__global__ __launch_bounds__(256) void k2_proj_sort(
    const ushort* __restrict__ Ab, int M, int rt,
    const ushort* __restrict__ W1t, const ushort* __restrict__ W2t,
    const float* __restrict__ b_msg, const float* __restrict__ pos,
    unsigned char* __restrict__ P1, ushort* __restrict__ P2b,
    const uint* __restrict__ bin_cursor, const uint* __restrict__ binned,
    uint* __restrict__ sorted, int* __restrict__ nstart, int* __restrict__ ncnt)
{
  // LDS (sort branch only; ~19 KB, GEMM occupancy unaffected)
  __shared__ ushort sdist[NCPY * BINF_CAP];   // 6 KB per-edge bf16 dist cache
  __shared__ uint   srt[CAP_OUT];             // 11.3 KB col-sorted recs
  __shared__ float  spos[64 * 3];             // 768 B
  __shared__ uint   h64[64], st64[64], lc64[64];
  __shared__ uint   ccnt[NCPY];
  __shared__ uint   stot;

  if ((int)blockIdx.x >= rt) {
    // ---- per-bin counting sort over the bin's 8 XCD segments ----
    const int bin = blockIdx.x - rt;
    const int col0 = bin * 64;
    const int ncol = min(64, M - col0);
    const int tid = threadIdx.x;

    if (tid < 64) { h64[tid] = 0; lc64[tid] = 0; }
    if (tid < NCPY)
      ccnt[tid] = min(bin_cursor[((size_t)tid * NBINS + bin) * CUR_STRIDE],
                      (uint)BINF_CAP);
    for (int i = tid; i < ncol * 3; i += 256) spos[i] = pos[(size_t)col0 * 3 + i];
    __syncthreads();

    // pass 1: dist (pos[row] gathers hide under co-resident GEMM) + histogram
    for (int c = 0; c < NCPY; ++c) {
      const int cnt = (int)ccnt[c];
      const uint* src = binned + ((size_t)c * NBINS + bin) * BINF_CAP;
      for (int i = tid; i < cnt; i += 256) {
        uint rc = src[i];
        uint row = rc & 0xffffu, c6 = (rc >> 16) & 63u;
        float dx = spos[c6 * 3 + 0] - pos[(size_t)row * 3 + 0];
        float dy = spos[c6 * 3 + 1] - pos[(size_t)row * 3 + 1];
        float dz = spos[c6 * 3 + 2] - pos[(size_t)row * 3 + 2];
        sdist[c * BINF_CAP + i] = f2bf(dx * dx + dy * dy + dz * dz);
        atomicAdd(&h64[c6], 1u);
      }
    }
    __syncthreads();

    // exclusive prefix over 64 buckets, each padded to 4 recs (16B align)
    if (tid == 0) {
      uint run = 0;
      for (int c = 0; c < 64; ++c) { st64[c] = run; run += (h64[c] + 3u) & ~3u; }
      stot = min(run, (uint)CAP_OUT);
    }
    __syncthreads();

    // pass 2: scatter into LDS at sorted positions (src re-read is L2-hot)
    for (int c = 0; c < NCPY; ++c) {
      const int cnt = (int)ccnt[c];
      const uint* src = binned + ((size_t)c * NBINS + bin) * BINF_CAP;
      for (int i = tid; i < cnt; i += 256) {
        uint rc = src[i];
        uint c6 = (rc >> 16) & 63u;
        uint p = st64[c6] + atomicAdd(&lc64[c6], 1u);
        if (p < CAP_OUT)
          srt[p] = ((rc & 0xffffu) << 16) | (uint)sdist[c * BINF_CAP + i];
      }
    }
    __syncthreads();

    // sequential writeout + per-node index
    const size_t obase = (size_t)bin * CAP_OUT;
    for (int i = tid; i < (int)stot; i += 256)
      sorted[obase + i] = srt[i];
    if (tid < ncol) {
      nstart[col0 + tid] = (int)(obase + st64[tid]);
      ncnt[col0 + tid] = (int)h64[tid];
    }
    return;
  }

  // ---- proj: P1 = fp8(Eb@W1t^T), P2b = bf16(Eb@W2t^T + b_msg) ----
  const int wv = threadIdx.x >> 6, lane = threadIdx.x & 63;
  const int q = lane >> 4, lr = lane & 15;
  const int m0 = blockIdx.x * 32;
  const int n0 = wv * 32;

  const ushort* Wt2[2] = {W1t, W2t};
  bf16x8 bfr[2][2][4];
#pragma unroll
  for (int ws = 0; ws < 2; ++ws)
#pragma unroll
    for (int nt = 0; nt < 2; ++nt) {
      int colc = n0 + nt * 16 + lr;
#pragma unroll
      for (int kc = 0; kc < 4; ++kc)
        bfr[ws][nt][kc] = load_frag(Wt2[ws] + colc * 128 + kc * 32 + q * 8);
    }

  floatx4 z = {0.f, 0.f, 0.f, 0.f};
  floatx4 acc[2][2][2];
#pragma unroll
  for (int ws = 0; ws < 2; ++ws)
#pragma unroll
    for (int mt = 0; mt < 2; ++mt)
#pragma unroll
      for (int nt = 0; nt < 2; ++nt) acc[ws][mt][nt] = z;

  const int r0 = min(m0 + lr, M - 1);
  const int r1 = min(m0 + 16 + lr, M - 1);
#pragma unroll
  for (int kc = 0; kc < 4; ++kc) {
    bf16x8 a0 = load_frag(Ab + (size_t)r0 * 128 + kc * 32 + q * 8);
    bf16x8 a1 = load_frag(Ab + (size_t)r1 * 128 + kc * 32 + q * 8);
#pragma unroll
    for (int ws = 0; ws < 2; ++ws)
#pragma unroll
      for (int nt = 0; nt < 2; ++nt) {
        acc[ws][0][nt] = __builtin_amdgcn_mfma_f32_16x16x32_bf16(a0, bfr[ws][nt][kc], acc[ws][0][nt], 0, 0, 0);
        acc[ws][1][nt] = __builtin_amdgcn_mfma_f32_16x16x32_bf16(a1, bfr[ws][nt][kc], acc[ws][1][nt], 0, 0, 0);
      }
  }

#pragma unroll
  for (int nt = 0; nt < 2; ++nt) {
    int colc = n0 + nt * 16 + lr;
    float bias = b_msg[colc];
#pragma unroll
    for (int mt = 0; mt < 2; ++mt)
#pragma unroll
      for (int i = 0; i < 4; ++i) {
        int r = m0 + mt * 16 + q * 4 + i;
        if (r < M) {
          int p8 = __builtin_amdgcn_cvt_pk_fp8_f32(acc[0][mt][nt][i], 0.f, 0, false);
          P1[(size_t)r * 128 + colc] = (unsigned char)(p8 & 0xff);
          P2b[(size_t)r * 128 + colc] = f2bf(acc[1][mt][nt][i] + bias);
        }
      }
  }
}

// ---- K3: aggregate — one wave per node, lane owns 2 channels, fp8 P1 gather ----
// Proven R21 kernel (58.5us ~= gather floor); contiguous sorted segments,
// persistent grid-stride waves, 8-deep batches.
__global__ __launch_bounds__(256) void aggregate(const int* __restrict__ ncnt,
                                                 const int* __restrict__ nstart,
                                                 const uint* __restrict__ sorted,
                                                 const unsigned char* __restrict__ P1,
                                                 const ushort* __restrict__ P2b,
                                                 const float* __restrict__ wd,
                                                 ushort* __restrict__ aggr, int M)
{
  const int lane = threadIdx.x & 63;
  const int ch = lane * 2;
  const int wid = blockIdx.x * 4 + (threadIdx.x >> 6);
  const int nw = gridDim.x * 4;

  float2 wl = *(const float2*)(wd + ch);
  floatx2 wv = {wl.x, wl.y};

  for (int n = wid; n < M; n += nw) {
    uint p2u = *(const uint*)(P2b + (size_t)n * 128 + ch);
    floatx2 p2 = {__int_as_float((int)(p2u << 16)),
                  __int_as_float((int)(p2u & 0xffff0000u))};

    const int cnt = ncnt[n];
    const uint* base = sorted + nstart[n];   // 16B aligned (starts padded to 4)

    floatx2 accA = {0.f, 0.f}, accB = {0.f, 0.f};

    // rec = (row<<16) | dist_bf16.  P1 row stride = 128B, so
    // voffset = ((rec>>16)<<7) | ch == ((rec>>9) & 0x7fff80) | ch  (32-bit)
    auto edge = [&](uint rec, floatx2& acc) {
      float d = __int_as_float((int)(rec << 16));        // bf16 dist in low 16
      uint off = ((rec >> 9) & 0x007fff80u) | (uint)ch;
      uint qu = (uint)*(const ushort*)(P1 + off);        // 2 fp8 channels
#if __has_builtin(__builtin_elementwise_fma)
      floatx2 u = __builtin_elementwise_fma((floatx2)(d), wv, p2);
#else
      floatx2 u = (floatx2)(d) * wv + p2;
#endif
      floatx2 t = cvtpk2(qu) + u;
      acc += pmax0(t);
    };

    int i = 0;
    for (; i + 8 <= cnt; i += 8) {
      uintx4 ra = __builtin_nontemporal_load((const uintx4*)(base + i));
      uintx4 rb = __builtin_nontemporal_load((const uintx4*)(base + i + 4));
      edge(ra.x, accA); edge(ra.y, accB); edge(ra.z, accA); edge(ra.w, accB);
      edge(rb.x, accA); edge(rb.y, accB); edge(rb.z, accA); edge(rb.w, accB);
    }
    for (; i < cnt; ++i) edge(base[i], accA);

    floatx2 acc = accA + accB;
    uint o = (uint)f2bf(acc.x) | ((uint)f2bf(acc.y) << 16);
    *(uint*)(aggr + (size_t)n * 128 + ch) = o;   // cacheable: gemm_upd reads it next
  }
}

// ---- K4: out = Eb@Wrt^T + relu(Eb@Wu1t^T + Gb@Wu2t^T + b_upd) ----
// 128 rows/block — weight fragments load once, amortized over 4 row-chunks
// (R22's one confirmed win, ~6.6us by delta decomposition).
__global__ __launch_bounds__(256) void gemm_upd_mfma(
    const ushort* __restrict__ Eb, const ushort* __restrict__ Gb, int M,
    const ushort* __restrict__ Wu1t, const ushort* __restrict__ Wu2t,
    const ushort* __restrict__ Wrt, const float* __restrict__ b_upd,
    float* __restrict__ out)
{
  const int wv = threadIdx.x >> 6, lane = threadIdx.x & 63;
  const int q = lane >> 4, lr = lane & 15;
  const int m0 = blockIdx.x * 128;
  const int n0 = wv * 32;

  bf16x8 b1[2][4], b2[2][4], br[2][4];
#pragma unroll
  for (int nt = 0; nt < 2; ++nt) {
    int colc = n0 + nt * 16 + lr;
#pragma unroll
    for (int kc = 0; kc < 4; ++kc) {
      b1[nt][kc] = load_frag(Wu1t + colc * 128 + kc * 32 + q * 8);
      b2[nt][kc] = load_frag(Wu2t + colc * 128 + kc * 32 + q * 8);
      br[nt][kc] = load_frag(Wrt  + colc * 128 + kc * 32 + q * 8);
    }
  }

  floatx4 z = {0.f, 0.f, 0.f, 0.f};

  for (int rc = 0; rc < 4; ++rc) {
    const int mb = m0 + rc * 32;
    if (mb >= M) break;

    floatx4 acc_u[2][2], acc_r[2][2];
#pragma unroll
    for (int mt = 0; mt < 2; ++mt)
#pragma unroll
      for (int nt = 0; nt < 2; ++nt) { acc_u[mt][nt] = z; acc_r[mt][nt] = z; }

    const int r0 = min(mb + lr, M - 1);
    const int r1 = min(mb + 16 + lr, M - 1);
#pragma unroll
    for (int kc = 0; kc < 4; ++kc) {
      bf16x8 ae0 = load_frag(Eb + (size_t)r0 * 128 + kc * 32 + q * 8);
      bf16x8 ae1 = load_frag(Eb + (size_t)r1 * 128 + kc * 32 + q * 8);
      bf16x8 ag0 = load_frag(Gb + (size_t)r0 * 128 + kc * 32 + q * 8);
      bf16x8 ag1 = load_frag(Gb + (size_t)r1 * 128 + kc * 32 + q * 8);
#pragma unroll
      for (int nt = 0; nt < 2; ++nt) {
        acc_u[0][nt] = __builtin_amdgcn_mfma_f32_16x16x32_bf16(ae0, b1[nt][kc], acc_u[0][nt], 0, 0, 0);
        acc_u[1][nt] = __builtin_amdgcn_mfma_f32_16x16x32_bf16(ae1, b1[nt][kc], acc_u[1][nt], 0, 0, 0);
        acc_u[0][nt] = __builtin_amdgcn_mfma_f32_16x16x32_bf16(ag0, b2[nt][kc], acc_u[0][nt], 0, 0, 0);
        acc_u[1][nt] = __builtin_amdgcn_mfma_f32_16x16x32_bf16(ag1, b2[nt][kc], acc_u[1][nt], 0, 0, 0);
        acc_r[0][nt] = __builtin_amdgcn_mfma_f32_16x16x32_bf16(ae0, br[nt][kc], acc_r[0][nt], 0, 0, 0);
        acc_r[1][nt] = __builtin_amdgcn_mfma_f32_16x16x32_bf16(ae1, br[nt][kc], acc_r[1][nt], 0, 0, 0);
      }
    }

#pragma unroll
    for (int nt = 0; nt < 2; ++nt) {
      int colc = n0 + nt * 16 + lr;
      float bias = b_upd[colc];
#pragma unroll
      for (int mt = 0; mt < 2; ++mt)
#pragma unroll
        for (int i = 0; i < 4; ++i) {
          int r = mb + mt * 16 + q * 4 + i;
          if (r < M)
            out[(size_t)r * 128 + colc] = acc_r[mt][nt][i] + fmaxf(acc_u[mt][nt][i] + bias, 0.f);
        }
    }
  }
}

extern "C" void kernel_launch(void* const* d_in, const int* in_sizes, int n_in,
                              void* d_out, int out_size, void* d_ws, size_t ws_size,
                              hipStream_t stream)
{
  const float* embed = (const float*)d_in[0];
  const float* pos   = (const float*)d_in[1];
  const int*   ei    = (const int*)d_in[2];
  const float* W_res = (const float*)d_in[3];
  const float* W_msg = (const float*)d_in[4];
  const float* b_msg = (const float*)d_in[5];
  const float* W_upd = (const float*)d_in[6];
  const float* b_upd = (const float*)d_in[7];
  float* out = (float*)d_out;

  const int M = in_sizes[0] / 128;   // 50000 (< 2^16, required for packed recs)
  const int E = in_sizes[2] / 2;     // 1.6M

  // Workspace (~72 MB); all segments 16-B aligned
  ushort* Eb = (ushort*)d_ws;                          // M*128 bf16
  unsigned char* P1f8 = (unsigned char*)(Eb + (size_t)M * 128);  // M*128 fp8
  ushort* P2b = (ushort*)(P1f8 + (size_t)M * 128);     // M*128 bf16
  ushort* Gb  = P2b + (size_t)M * 128;                 // M*128 bf16
  ushort* Wt  = Gb  + (size_t)M * 128;                 // 5 x 128x128 bf16 (transposed)
  uint*   binned = (uint*)(Wt + 5 * 16384);            // NCPY*NBINS*BINF_CAP
  uint*   sorted = binned + (size_t)NCPY * NBINS * BINF_CAP;  // NBINS*CAP_OUT
  int*    nstart = (int*)(sorted + (size_t)NBINS * CAP_OUT);  // M
  int*    ncnt   = nstart + M;                         // M
  uint*   bin_cursor = (uint*)(ncnt + M);              // NCPY*NBINS*CUR_STRIDE

  // zero padded per-copy bin cursors (1 MB)
  (void)hipMemsetAsync(bin_cursor, 0,
                       (size_t)NCPY * NBINS * CUR_STRIDE * sizeof(uint), stream);

  WSrc wsrc;
  wsrc.s[0] = W_msg;               // W1
  wsrc.s[1] = W_msg + 128 * 128;   // W2
  wsrc.s[2] = W_res;               // Wres
  wsrc.s[3] = W_upd;               // Wu1
  wsrc.s[4] = W_upd + 128 * 128;   // Wu2

  int n4 = M * 128 / 4;
  int nb_cast = (n4 + 2047) / 2048;          // grid-strided: 8 float4/thread
  int bb = (E + EPB - 1) / EPB;              // 196 binpass blocks
  // fused cast + binpass: binpass blocks first (critical path),
  // cast blocks fill the machine around them
  k01_cast_bin<<<bb + nb_cast + 5, 256, 0, stream>>>(
      embed, Eb, n4, nb_cast, wsrc, Wt, ei, E, bin_cursor, binned, bb);

  int rt = (M + 31) / 32;
  int nb2 = (M + 63) / 64;   // 782 used fine bins
  k2_proj_sort<<<rt + nb2, 256, 0, stream>>>(
      Eb, M, rt, Wt, Wt + 16384, b_msg, pos, P1f8, P2b,
      bin_cursor, binned, sorted, nstart, ncnt);

  // persistent waves: 2048 blocks x 4 waves; each wave strides ~6 nodes
  int ab = min((M + 3) / 4, 2048);
  aggregate<<<ab, 256, 0, stream>>>(ncnt, nstart, sorted, P1f8, P2b,
                                    W_msg + 256 * 128, Gb, M);

  int rt4 = (M + 127) / 128;   // 391 blocks, weights amortized 4x
  gemm_upd_mfma<<<rt4, 256, 0, stream>>>(Eb, Gb, M, Wt + 3 * 16384, Wt + 4 * 16384,
                                         Wt + 2 * 16384, b_upd, out);
}